// Round 1
// baseline (7061.303 us; speedup 1.0000x reference)
//
#include <hip/hip_runtime.h>
#include <math.h>

static constexpr int N_NODES = 100000;
static constexpr int NNZ     = 1600000;
static constexpr int CFB     = 8192;

__device__ __forceinline__ float lrelu(float x) { return x >= 0.0f ? x : 0.01f * x; }

// ---------------- SpMM: side = A @ ego (COO, atomic scatter) ----------------
template<int DIN>
__global__ __launch_bounds__(256)
void spmm_kernel(const float* __restrict__ ego,
                 const int* __restrict__ erows,
                 const int* __restrict__ ecols,
                 const float* __restrict__ evals,
                 float* __restrict__ side) {
  constexpr int LPE = DIN / 4;              // lanes per edge (float4 each)
  unsigned tid = blockIdx.x * 256u + threadIdx.x;
  unsigned e = tid / LPE;
  unsigned g = tid % LPE;
  if (e >= (unsigned)NNZ) return;
  int r = erows[e];
  int c = ecols[e];
  float v = evals[e];
  float4 x = *reinterpret_cast<const float4*>(ego + (size_t)c * DIN + g * 4u);
  float* dst = side + (size_t)r * DIN + g * 4u;
  unsafeAtomicAdd(dst + 0, v * x.x);
  unsafeAtomicAdd(dst + 1, v * x.y);
  unsafeAtomicAdd(dst + 2, v * x.z);
  unsafeAtomicAdd(dst + 3, v * x.w);
}

// -------- bi-interaction: out = lrelu((e+s)@W1+b1) + lrelu((e*s)@W2+b2) -----
template<int DIN, int DOUT>
__global__ __launch_bounds__(256)
void bi_kernel(const float* __restrict__ ego,
               const float* __restrict__ side,
               const float* __restrict__ W1, const float* __restrict__ b1,
               const float* __restrict__ W2, const float* __restrict__ b2,
               float* __restrict__ out) {
  constexpr int R   = 32;                 // rows per block
  constexpr int LD  = DIN + 4;            // padded LDS stride (bank spread)
  constexpr int CG  = DOUT / 4;           // column groups (4 cols each)
  constexpr int RG  = 256 / CG;           // row groups
  constexpr int RPT = R / RG;             // rows per thread
  __shared__ float h1[R][LD];
  __shared__ float h2[R][LD];

  const int row0 = blockIdx.x * R;
  const int tid  = threadIdx.x;

  // fill h1 = ego + side, h2 = ego * side  (float4, coalesced)
  constexpr int ELEMS4 = R * DIN / 4;
  for (int i = tid; i < ELEMS4; i += 256) {
    int rr = i / (DIN / 4);
    int kk = (i % (DIN / 4)) * 4;
    float4 e4 = *reinterpret_cast<const float4*>(ego  + (size_t)(row0 + rr) * DIN + kk);
    float4 s4 = *reinterpret_cast<const float4*>(side + (size_t)(row0 + rr) * DIN + kk);
    h1[rr][kk + 0] = e4.x + s4.x;  h2[rr][kk + 0] = e4.x * s4.x;
    h1[rr][kk + 1] = e4.y + s4.y;  h2[rr][kk + 1] = e4.y * s4.y;
    h1[rr][kk + 2] = e4.z + s4.z;  h2[rr][kk + 2] = e4.z * s4.z;
    h1[rr][kk + 3] = e4.w + s4.w;  h2[rr][kk + 3] = e4.w * s4.w;
  }
  __syncthreads();

  const int cg = tid % CG;
  const int rg = tid / CG;
  const int c0 = cg * 4;

  float acc1[RPT][4];
  float acc2[RPT][4];
  #pragma unroll
  for (int rr = 0; rr < RPT; ++rr)
    #pragma unroll
    for (int j = 0; j < 4; ++j) { acc1[rr][j] = 0.f; acc2[rr][j] = 0.f; }

  for (int k = 0; k < DIN; ++k) {
    float4 w1 = *reinterpret_cast<const float4*>(W1 + (size_t)k * DOUT + c0);
    float4 w2 = *reinterpret_cast<const float4*>(W2 + (size_t)k * DOUT + c0);
    #pragma unroll
    for (int rr = 0; rr < RPT; ++rr) {
      int r = rg * RPT + rr;
      float a = h1[r][k];
      float m = h2[r][k];
      acc1[rr][0] += a * w1.x;  acc1[rr][1] += a * w1.y;
      acc1[rr][2] += a * w1.z;  acc1[rr][3] += a * w1.w;
      acc2[rr][0] += m * w2.x;  acc2[rr][1] += m * w2.y;
      acc2[rr][2] += m * w2.z;  acc2[rr][3] += m * w2.w;
    }
  }

  float4 bb1 = *reinterpret_cast<const float4*>(b1 + c0);
  float4 bb2 = *reinterpret_cast<const float4*>(b2 + c0);
  #pragma unroll
  for (int rr = 0; rr < RPT; ++rr) {
    int r = row0 + rg * RPT + rr;
    float4 o;
    o.x = lrelu(acc1[rr][0] + bb1.x) + lrelu(acc2[rr][0] + bb2.x);
    o.y = lrelu(acc1[rr][1] + bb1.y) + lrelu(acc2[rr][1] + bb2.y);
    o.z = lrelu(acc1[rr][2] + bb1.z) + lrelu(acc2[rr][2] + bb2.z);
    o.w = lrelu(acc1[rr][3] + bb1.w) + lrelu(acc2[rr][3] + bb2.w);
    *reinterpret_cast<float4*>(out + (size_t)r * DOUT + c0) = o;
  }
}

// -------- per-layer score accumulation over the 8192 (u,p,n) triples --------
template<bool NORM>
__global__ __launch_bounds__(256)
void score_kernel(const float* __restrict__ emb, int dim,
                  const int* __restrict__ uid, const int* __restrict__ pid,
                  const int* __restrict__ nid,
                  float* __restrict__ pos, float* __restrict__ neg,
                  float* __restrict__ l2) {
  int i = blockIdx.x * 4 + (threadIdx.x >> 6);
  int lane = threadIdx.x & 63;
  if (i >= CFB) return;
  const float* u = emb + (size_t)uid[i] * dim;
  const float* p = emb + (size_t)pid[i] * dim;
  const float* g = emb + (size_t)nid[i] * dim;
  float up = 0, un = 0, uu = 0, pp = 0, nn = 0;
  for (int d = lane; d < dim; d += 64) {
    float a = u[d], b = p[d], c = g[d];
    up += a * b;  un += a * c;
    uu += a * a;  pp += b * b;  nn += c * c;
  }
  #pragma unroll
  for (int off = 32; off > 0; off >>= 1) {
    up += __shfl_xor(up, off);
    un += __shfl_xor(un, off);
    uu += __shfl_xor(uu, off);
    pp += __shfl_xor(pp, off);
    nn += __shfl_xor(nn, off);
  }
  if (lane == 0) {
    if (NORM) {
      float mu = fmaxf(sqrtf(uu), 1e-12f);
      float mp = fmaxf(sqrtf(pp), 1e-12f);
      float mn = fmaxf(sqrtf(nn), 1e-12f);
      pos[i] += up / (mu * mp);
      neg[i] += un / (mu * mn);
      l2[i]  += uu / (mu * mu) + pp / (mp * mp) + nn / (mn * mn);
    } else {
      pos[i] = up;
      neg[i] = un;
      l2[i]  = uu + pp + nn;
    }
  }
}

// ---------------------------- final loss reduce -----------------------------
__global__ __launch_bounds__(256)
void loss_kernel(const float* __restrict__ pos, const float* __restrict__ neg,
                 const float* __restrict__ l2, float* __restrict__ out) {
  __shared__ float s1[256];
  __shared__ float s2[256];
  int tid = threadIdx.x;
  float cf = 0.f, reg = 0.f;
  for (int i = tid; i < CFB; i += 256) {
    float x = pos[i] - neg[i];
    // -log_sigmoid(x) = softplus(-x), numerically stable
    float sp = (x > 0.f) ? log1pf(expf(-x)) : (-x + log1pf(expf(x)));
    cf  += sp;
    reg += l2[i];
  }
  s1[tid] = cf; s2[tid] = reg;
  __syncthreads();
  for (int s = 128; s > 0; s >>= 1) {
    if (tid < s) { s1[tid] += s1[tid + s]; s2[tid] += s2[tid + s]; }
    __syncthreads();
  }
  if (tid == 0)
    out[0] = s1[0] / (float)CFB + 1e-5f * (0.5f * s2[0] / (float)CFB);
}

extern "C" void kernel_launch(void* const* d_in, const int* in_sizes, int n_in,
                              void* d_out, int out_size, void* d_ws, size_t ws_size,
                              hipStream_t stream) {
  const float* embed = (const float*)d_in[0];
  const float* W1_0 = (const float*)d_in[1];
  const float* b1_0 = (const float*)d_in[2];
  const float* W2_0 = (const float*)d_in[3];
  const float* b2_0 = (const float*)d_in[4];
  const float* W1_1 = (const float*)d_in[5];
  const float* b1_1 = (const float*)d_in[6];
  const float* W2_1 = (const float*)d_in[7];
  const float* b2_1 = (const float*)d_in[8];
  const float* W1_2 = (const float*)d_in[9];
  const float* b1_2 = (const float*)d_in[10];
  const float* W2_2 = (const float*)d_in[11];
  const float* b2_2 = (const float*)d_in[12];
  const int*   erows = (const int*)d_in[13];
  const int*   ecols = (const int*)d_in[14];
  const float* evals = (const float*)d_in[15];
  const int*   uid = (const int*)d_in[16];
  const int*   pid = (const int*)d_in[17];
  const int*   nid = (const int*)d_in[18];

  float* side = (float*)d_ws;
  float* egoA = side + (size_t)N_NODES * 128;
  float* egoB = egoA + (size_t)N_NODES * 128;
  float* posb = egoB + (size_t)N_NODES * 128;
  float* negb = posb + CFB;
  float* l2b  = negb + CFB;

  // layer-0 (raw embedding) contribution; initializes accumulators
  score_kernel<false><<<CFB / 4, 256, 0, stream>>>(embed, 128, uid, pid, nid, posb, negb, l2b);

  // ---- layer 0: 128 -> 128 ----
  hipMemsetAsync(side, 0, (size_t)N_NODES * 128 * sizeof(float), stream);
  spmm_kernel<128><<<(NNZ * 32) / 256, 256, 0, stream>>>(embed, erows, ecols, evals, side);
  bi_kernel<128, 128><<<N_NODES / 32, 256, 0, stream>>>(embed, side, W1_0, b1_0, W2_0, b2_0, egoA);
  score_kernel<true><<<CFB / 4, 256, 0, stream>>>(egoA, 128, uid, pid, nid, posb, negb, l2b);

  // ---- layer 1: 128 -> 64 ----
  hipMemsetAsync(side, 0, (size_t)N_NODES * 128 * sizeof(float), stream);
  spmm_kernel<128><<<(NNZ * 32) / 256, 256, 0, stream>>>(egoA, erows, ecols, evals, side);
  bi_kernel<128, 64><<<N_NODES / 32, 256, 0, stream>>>(egoA, side, W1_1, b1_1, W2_1, b2_1, egoB);
  score_kernel<true><<<CFB / 4, 256, 0, stream>>>(egoB, 64, uid, pid, nid, posb, negb, l2b);

  // ---- layer 2: 64 -> 32 ----
  hipMemsetAsync(side, 0, (size_t)N_NODES * 64 * sizeof(float), stream);
  spmm_kernel<64><<<(NNZ * 16) / 256, 256, 0, stream>>>(egoB, erows, ecols, evals, side);
  bi_kernel<64, 32><<<N_NODES / 32, 256, 0, stream>>>(egoB, side, W1_2, b1_2, W2_2, b2_2, egoA);
  score_kernel<true><<<CFB / 4, 256, 0, stream>>>(egoA, 32, uid, pid, nid, posb, negb, l2b);

  loss_kernel<<<1, 256, 0, stream>>>(posb, negb, l2b, (float*)d_out);
}

// Round 2
// 879.533 us; speedup vs baseline: 8.0285x; 8.0285x over previous
//
#include <hip/hip_runtime.h>
#include <math.h>

static constexpr int N_NODES = 100000;
static constexpr int NNZ     = 1600000;
static constexpr int CFB     = 8192;
static constexpr int NBLK    = (N_NODES + 255) / 256;   // 391 scan blocks

__device__ __forceinline__ float lrelu(float x) { return x >= 0.0f ? x : 0.01f * x; }

// ---------------------- CSR build: histogram ---------------------------------
__global__ __launch_bounds__(256)
void hist_kernel(const int* __restrict__ erows, int* __restrict__ cnt) {
  int i = blockIdx.x * 256 + threadIdx.x;
  if (i < NNZ) atomicAdd(&cnt[erows[i]], 1);
}

// per-block sums of cnt
__global__ __launch_bounds__(256)
void scan_reduce(const int* __restrict__ cnt, int* __restrict__ bsum) {
  __shared__ int s[256];
  int i = blockIdx.x * 256 + threadIdx.x;
  s[threadIdx.x] = (i < N_NODES) ? cnt[i] : 0;
  __syncthreads();
  for (int st = 128; st > 0; st >>= 1) {
    if (threadIdx.x < st) s[threadIdx.x] += s[threadIdx.x + st];
    __syncthreads();
  }
  if (threadIdx.x == 0) bsum[blockIdx.x] = s[0];
}

// exclusive scan of the (<=512) block sums, in place
__global__ __launch_bounds__(512)
void scan_top(int* __restrict__ bsum) {
  __shared__ int s[512];
  int t = threadIdx.x;
  int v0 = (t < NBLK) ? bsum[t] : 0;
  s[t] = v0;
  __syncthreads();
  for (int off = 1; off < 512; off <<= 1) {
    int v = (t >= off) ? s[t - off] : 0;
    __syncthreads();
    s[t] += v;
    __syncthreads();
  }
  if (t < NBLK) bsum[t] = s[t] - v0;   // exclusive
}

// per-block exclusive scan + block offset -> row_ptr; also init scatter cursor
__global__ __launch_bounds__(256)
void scan_final(int* __restrict__ cnt_off,   // in: counts, out: scatter cursor
                int* __restrict__ row_ptr,
                const int* __restrict__ bsum) {
  __shared__ int s[256];
  int t = threadIdx.x;
  int i = blockIdx.x * 256 + t;
  int v = (i < N_NODES) ? cnt_off[i] : 0;
  s[t] = v;
  __syncthreads();
  for (int off = 1; off < 256; off <<= 1) {
    int x = (t >= off) ? s[t - off] : 0;
    __syncthreads();
    s[t] += x;
    __syncthreads();
  }
  int excl = s[t] - v + bsum[blockIdx.x];
  if (i < N_NODES) { row_ptr[i] = excl; cnt_off[i] = excl; }
  if (i == 0) row_ptr[N_NODES] = NNZ;
}

__global__ __launch_bounds__(256)
void scatter_kernel(const int* __restrict__ erows, const int* __restrict__ ecols,
                    const float* __restrict__ evals, int* __restrict__ cursor,
                    int* __restrict__ scol, float* __restrict__ sval) {
  int i = blockIdx.x * 256 + threadIdx.x;
  if (i < NNZ) {
    int r = erows[i];
    int p = atomicAdd(&cursor[r], 1);
    scol[p] = ecols[i];
    sval[p] = evals[i];
  }
}

// ---------------- SpMM (CSR): one wave per row, no atomics ------------------
template<int DIN>
__global__ __launch_bounds__(256)
void spmm_csr(const float* __restrict__ ego,
              const int* __restrict__ row_ptr,
              const int* __restrict__ scol,
              const float* __restrict__ sval,
              float* __restrict__ side) {
  int row  = blockIdx.x * 4 + (threadIdx.x >> 6);
  int lane = threadIdx.x & 63;
  if (row >= N_NODES) return;
  int j0 = row_ptr[row], j1 = row_ptr[row + 1];
  if constexpr (DIN == 128) {
    float ax = 0.f, ay = 0.f;
    #pragma unroll 2
    for (int j = j0; j < j1; ++j) {
      int   c = scol[j];
      float v = sval[j];
      float2 x = *reinterpret_cast<const float2*>(ego + (size_t)c * 128 + lane * 2);
      ax += v * x.x;  ay += v * x.y;
    }
    float2 o; o.x = ax; o.y = ay;
    *reinterpret_cast<float2*>(side + (size_t)row * 128 + lane * 2) = o;
  } else {
    float a = 0.f;
    #pragma unroll 2
    for (int j = j0; j < j1; ++j)
      a += sval[j] * ego[(size_t)scol[j] * DIN + lane];
    side[(size_t)row * DIN + lane] = a;
  }
}

// -------- bi-interaction: out = lrelu((e+s)@W1+b1) + lrelu((e*s)@W2+b2) -----
template<int DIN, int DOUT>
__global__ __launch_bounds__(256)
void bi_kernel(const float* __restrict__ ego,
               const float* __restrict__ side,
               const float* __restrict__ W1, const float* __restrict__ b1,
               const float* __restrict__ W2, const float* __restrict__ b2,
               float* __restrict__ out) {
  constexpr int R   = 32;
  constexpr int LD  = DIN + 4;
  constexpr int CG  = DOUT / 4;
  constexpr int RG  = 256 / CG;
  constexpr int RPT = R / RG;
  __shared__ float h1[R][LD];
  __shared__ float h2[R][LD];

  const int row0 = blockIdx.x * R;
  const int tid  = threadIdx.x;

  constexpr int ELEMS4 = R * DIN / 4;
  for (int i = tid; i < ELEMS4; i += 256) {
    int rr = i / (DIN / 4);
    int kk = (i % (DIN / 4)) * 4;
    float4 e4 = *reinterpret_cast<const float4*>(ego  + (size_t)(row0 + rr) * DIN + kk);
    float4 s4 = *reinterpret_cast<const float4*>(side + (size_t)(row0 + rr) * DIN + kk);
    h1[rr][kk + 0] = e4.x + s4.x;  h2[rr][kk + 0] = e4.x * s4.x;
    h1[rr][kk + 1] = e4.y + s4.y;  h2[rr][kk + 1] = e4.y * s4.y;
    h1[rr][kk + 2] = e4.z + s4.z;  h2[rr][kk + 2] = e4.z * s4.z;
    h1[rr][kk + 3] = e4.w + s4.w;  h2[rr][kk + 3] = e4.w * s4.w;
  }
  __syncthreads();

  const int cg = tid % CG;
  const int rg = tid / CG;
  const int c0 = cg * 4;

  float acc1[RPT][4];
  float acc2[RPT][4];
  #pragma unroll
  for (int rr = 0; rr < RPT; ++rr)
    #pragma unroll
    for (int j = 0; j < 4; ++j) { acc1[rr][j] = 0.f; acc2[rr][j] = 0.f; }

  for (int k = 0; k < DIN; ++k) {
    float4 w1 = *reinterpret_cast<const float4*>(W1 + (size_t)k * DOUT + c0);
    float4 w2 = *reinterpret_cast<const float4*>(W2 + (size_t)k * DOUT + c0);
    #pragma unroll
    for (int rr = 0; rr < RPT; ++rr) {
      int r = rg * RPT + rr;
      float a = h1[r][k];
      float m = h2[r][k];
      acc1[rr][0] += a * w1.x;  acc1[rr][1] += a * w1.y;
      acc1[rr][2] += a * w1.z;  acc1[rr][3] += a * w1.w;
      acc2[rr][0] += m * w2.x;  acc2[rr][1] += m * w2.y;
      acc2[rr][2] += m * w2.z;  acc2[rr][3] += m * w2.w;
    }
  }

  float4 bb1 = *reinterpret_cast<const float4*>(b1 + c0);
  float4 bb2 = *reinterpret_cast<const float4*>(b2 + c0);
  #pragma unroll
  for (int rr = 0; rr < RPT; ++rr) {
    int r = row0 + rg * RPT + rr;
    float4 o;
    o.x = lrelu(acc1[rr][0] + bb1.x) + lrelu(acc2[rr][0] + bb2.x);
    o.y = lrelu(acc1[rr][1] + bb1.y) + lrelu(acc2[rr][1] + bb2.y);
    o.z = lrelu(acc1[rr][2] + bb1.z) + lrelu(acc2[rr][2] + bb2.z);
    o.w = lrelu(acc1[rr][3] + bb1.w) + lrelu(acc2[rr][3] + bb2.w);
    *reinterpret_cast<float4*>(out + (size_t)r * DOUT + c0) = o;
  }
}

// -------- per-layer score accumulation over the 8192 (u,p,n) triples --------
template<bool NORM>
__global__ __launch_bounds__(256)
void score_kernel(const float* __restrict__ emb, int dim,
                  const int* __restrict__ uid, const int* __restrict__ pid,
                  const int* __restrict__ nid,
                  float* __restrict__ pos, float* __restrict__ neg,
                  float* __restrict__ l2) {
  int i = blockIdx.x * 4 + (threadIdx.x >> 6);
  int lane = threadIdx.x & 63;
  if (i >= CFB) return;
  const float* u = emb + (size_t)uid[i] * dim;
  const float* p = emb + (size_t)pid[i] * dim;
  const float* g = emb + (size_t)nid[i] * dim;
  float up = 0, un = 0, uu = 0, pp = 0, nn = 0;
  for (int d = lane; d < dim; d += 64) {
    float a = u[d], b = p[d], c = g[d];
    up += a * b;  un += a * c;
    uu += a * a;  pp += b * b;  nn += c * c;
  }
  #pragma unroll
  for (int off = 32; off > 0; off >>= 1) {
    up += __shfl_xor(up, off);
    un += __shfl_xor(un, off);
    uu += __shfl_xor(uu, off);
    pp += __shfl_xor(pp, off);
    nn += __shfl_xor(nn, off);
  }
  if (lane == 0) {
    if (NORM) {
      float mu = fmaxf(sqrtf(uu), 1e-12f);
      float mp = fmaxf(sqrtf(pp), 1e-12f);
      float mn = fmaxf(sqrtf(nn), 1e-12f);
      pos[i] += up / (mu * mp);
      neg[i] += un / (mu * mn);
      l2[i]  += uu / (mu * mu) + pp / (mp * mp) + nn / (mn * mn);
    } else {
      pos[i] = up;
      neg[i] = un;
      l2[i]  = uu + pp + nn;
    }
  }
}

// ---------------------------- final loss reduce -----------------------------
__global__ __launch_bounds__(256)
void loss_kernel(const float* __restrict__ pos, const float* __restrict__ neg,
                 const float* __restrict__ l2, float* __restrict__ out) {
  __shared__ float s1[256];
  __shared__ float s2[256];
  int tid = threadIdx.x;
  float cf = 0.f, reg = 0.f;
  for (int i = tid; i < CFB; i += 256) {
    float x = pos[i] - neg[i];
    float sp = (x > 0.f) ? log1pf(expf(-x)) : (-x + log1pf(expf(x)));
    cf  += sp;
    reg += l2[i];
  }
  s1[tid] = cf; s2[tid] = reg;
  __syncthreads();
  for (int s = 128; s > 0; s >>= 1) {
    if (tid < s) { s1[tid] += s1[tid + s]; s2[tid] += s2[tid + s]; }
    __syncthreads();
  }
  if (tid == 0)
    out[0] = s1[0] / (float)CFB + 1e-5f * (0.5f * s2[0] / (float)CFB);
}

extern "C" void kernel_launch(void* const* d_in, const int* in_sizes, int n_in,
                              void* d_out, int out_size, void* d_ws, size_t ws_size,
                              hipStream_t stream) {
  const float* embed = (const float*)d_in[0];
  const float* W1_0 = (const float*)d_in[1];
  const float* b1_0 = (const float*)d_in[2];
  const float* W2_0 = (const float*)d_in[3];
  const float* b2_0 = (const float*)d_in[4];
  const float* W1_1 = (const float*)d_in[5];
  const float* b1_1 = (const float*)d_in[6];
  const float* W2_1 = (const float*)d_in[7];
  const float* b2_1 = (const float*)d_in[8];
  const float* W1_2 = (const float*)d_in[9];
  const float* b1_2 = (const float*)d_in[10];
  const float* W2_2 = (const float*)d_in[11];
  const float* b2_2 = (const float*)d_in[12];
  const int*   erows = (const int*)d_in[13];
  const int*   ecols = (const int*)d_in[14];
  const float* evals = (const float*)d_in[15];
  const int*   uid = (const int*)d_in[16];
  const int*   pid = (const int*)d_in[17];
  const int*   nid = (const int*)d_in[18];

  // ---------------- workspace layout (~142 MB) ----------------
  float* side    = (float*)d_ws;                             // N*128 f32
  float* egoA    = side + (size_t)N_NODES * 128;             // N*128 f32
  float* egoB    = egoA + (size_t)N_NODES * 128;             // N*64  f32
  float* fend    = egoB + (size_t)N_NODES * 64;
  int*   row_ptr = (int*)fend;                               // N+1
  int*   cursor  = row_ptr + (N_NODES + 1);                  // N (hist, then scatter cursor)
  int*   bsum    = cursor + N_NODES;                         // 512
  int*   scol    = bsum + 512;                               // NNZ
  float* sval    = (float*)(scol + NNZ);                     // NNZ
  float* posb    = sval + NNZ;
  float* negb    = posb + CFB;
  float* l2b     = negb + CFB;

  // ---------------- build CSR (once per call) ----------------
  hipMemsetAsync(cursor, 0, (size_t)N_NODES * sizeof(int), stream);
  hist_kernel<<<(NNZ + 255) / 256, 256, 0, stream>>>(erows, cursor);
  scan_reduce<<<NBLK, 256, 0, stream>>>(cursor, bsum);
  scan_top<<<1, 512, 0, stream>>>(bsum);
  scan_final<<<NBLK, 256, 0, stream>>>(cursor, row_ptr, bsum);
  scatter_kernel<<<(NNZ + 255) / 256, 256, 0, stream>>>(erows, ecols, evals, cursor, scol, sval);

  // layer-0 (raw embedding) contribution; initializes accumulators
  score_kernel<false><<<CFB / 4, 256, 0, stream>>>(embed, 128, uid, pid, nid, posb, negb, l2b);

  // ---- layer 0: 128 -> 128 ----
  spmm_csr<128><<<(N_NODES + 3) / 4, 256, 0, stream>>>(embed, row_ptr, scol, sval, side);
  bi_kernel<128, 128><<<N_NODES / 32, 256, 0, stream>>>(embed, side, W1_0, b1_0, W2_0, b2_0, egoA);
  score_kernel<true><<<CFB / 4, 256, 0, stream>>>(egoA, 128, uid, pid, nid, posb, negb, l2b);

  // ---- layer 1: 128 -> 64 ----
  spmm_csr<128><<<(N_NODES + 3) / 4, 256, 0, stream>>>(egoA, row_ptr, scol, sval, side);
  bi_kernel<128, 64><<<N_NODES / 32, 256, 0, stream>>>(egoA, side, W1_1, b1_1, W2_1, b2_1, egoB);
  score_kernel<true><<<CFB / 4, 256, 0, stream>>>(egoB, 64, uid, pid, nid, posb, negb, l2b);

  // ---- layer 2: 64 -> 32 ----
  spmm_csr<64><<<(N_NODES + 3) / 4, 256, 0, stream>>>(egoB, row_ptr, scol, sval, side);
  bi_kernel<64, 32><<<N_NODES / 32, 256, 0, stream>>>(egoB, side, W1_2, b1_2, W2_2, b2_2, egoA);
  score_kernel<true><<<CFB / 4, 256, 0, stream>>>(egoA, 32, uid, pid, nid, posb, negb, l2b);

  loss_kernel<<<1, 256, 0, stream>>>(posb, negb, l2b, (float*)d_out);
}

// Round 3
// 521.698 us; speedup vs baseline: 13.5352x; 1.6859x over previous
//
#include <hip/hip_runtime.h>
#include <math.h>

static constexpr int N_NODES = 100000;
static constexpr int NNZ     = 1600000;
static constexpr int CFB     = 8192;
static constexpr int NBLK    = (N_NODES + 255) / 256;   // 391 scan blocks

typedef short bf16x8 __attribute__((ext_vector_type(8)));
typedef float f32x4  __attribute__((ext_vector_type(4)));

__device__ __forceinline__ float lrelu(float x) { return x >= 0.0f ? x : 0.01f * x; }

__device__ __forceinline__ unsigned short f2bf(float x) {
  unsigned u = __float_as_uint(x);
  u += 0x7FFFu + ((u >> 16) & 1u);          // round-to-nearest-even
  return (unsigned short)(u >> 16);
}
__device__ __forceinline__ float bf2f(unsigned short h) {
  return __uint_as_float(((unsigned)h) << 16);
}
__device__ __forceinline__ unsigned pack2(float x, float y) {
  return (unsigned)f2bf(x) | ((unsigned)f2bf(y) << 16);
}

// ------------------------- f32 -> bf16 convert ------------------------------
__global__ __launch_bounds__(256)
void cvt_bf16_kernel(const float* __restrict__ in, unsigned short* __restrict__ out, int n4) {
  int i = blockIdx.x * 256 + threadIdx.x;
  if (i < n4) {
    float4 v = reinterpret_cast<const float4*>(in)[i];
    uint2 o; o.x = pack2(v.x, v.y); o.y = pack2(v.z, v.w);
    reinterpret_cast<uint2*>(out)[i] = o;
  }
}

// ---------------------- CSR build ---------------------------------
__global__ __launch_bounds__(256)
void hist_kernel(const int* __restrict__ erows, int* __restrict__ cnt) {
  int i = blockIdx.x * 256 + threadIdx.x;
  if (i < NNZ) atomicAdd(&cnt[erows[i]], 1);
}

__global__ __launch_bounds__(256)
void scan_reduce(const int* __restrict__ cnt, int* __restrict__ bsum) {
  __shared__ int s[256];
  int i = blockIdx.x * 256 + threadIdx.x;
  s[threadIdx.x] = (i < N_NODES) ? cnt[i] : 0;
  __syncthreads();
  for (int st = 128; st > 0; st >>= 1) {
    if (threadIdx.x < st) s[threadIdx.x] += s[threadIdx.x + st];
    __syncthreads();
  }
  if (threadIdx.x == 0) bsum[blockIdx.x] = s[0];
}

__global__ __launch_bounds__(512)
void scan_top(int* __restrict__ bsum) {
  __shared__ int s[512];
  int t = threadIdx.x;
  int v0 = (t < NBLK) ? bsum[t] : 0;
  s[t] = v0;
  __syncthreads();
  for (int off = 1; off < 512; off <<= 1) {
    int v = (t >= off) ? s[t - off] : 0;
    __syncthreads();
    s[t] += v;
    __syncthreads();
  }
  if (t < NBLK) bsum[t] = s[t] - v0;
}

__global__ __launch_bounds__(256)
void scan_final(int* __restrict__ cnt_off, int* __restrict__ row_ptr,
                const int* __restrict__ bsum) {
  __shared__ int s[256];
  int t = threadIdx.x;
  int i = blockIdx.x * 256 + t;
  int v = (i < N_NODES) ? cnt_off[i] : 0;
  s[t] = v;
  __syncthreads();
  for (int off = 1; off < 256; off <<= 1) {
    int x = (t >= off) ? s[t - off] : 0;
    __syncthreads();
    s[t] += x;
    __syncthreads();
  }
  int excl = s[t] - v + bsum[blockIdx.x];
  if (i < N_NODES) { row_ptr[i] = excl; cnt_off[i] = excl; }
  if (i == 0) row_ptr[N_NODES] = NNZ;
}

__global__ __launch_bounds__(256)
void scatter_kernel(const int* __restrict__ erows, const int* __restrict__ ecols,
                    const float* __restrict__ evals, int* __restrict__ cursor,
                    int* __restrict__ scol, float* __restrict__ sval) {
  int i = blockIdx.x * 256 + threadIdx.x;
  if (i < NNZ) {
    int r = erows[i];
    int p = atomicAdd(&cursor[r], 1);
    scol[p] = ecols[i];
    sval[p] = evals[i];
  }
}

// ---------------- SpMM (CSR, bf16): one wave per row ------------------------
template<int DIN>
__global__ __launch_bounds__(256)
void spmm_bf16(const unsigned short* __restrict__ ego,
               const int* __restrict__ row_ptr,
               const int* __restrict__ scol,
               const float* __restrict__ sval,
               unsigned short* __restrict__ side) {
  int row  = blockIdx.x * 4 + (threadIdx.x >> 6);
  int lane = threadIdx.x & 63;
  if (row >= N_NODES) return;
  int j0 = row_ptr[row], j1 = row_ptr[row + 1];
  if constexpr (DIN == 128) {
    float ax = 0.f, ay = 0.f;
    #pragma unroll 4
    for (int j = j0; j < j1; ++j) {
      int   c = scol[j];
      float v = sval[j];
      unsigned x = *reinterpret_cast<const unsigned*>(ego + (size_t)c * 128 + lane * 2);
      ax += v * bf2f((unsigned short)(x & 0xFFFFu));
      ay += v * bf2f((unsigned short)(x >> 16));
    }
    *reinterpret_cast<unsigned*>(side + (size_t)row * 128 + lane * 2) = pack2(ax, ay);
  } else {
    float a = 0.f;
    #pragma unroll 4
    for (int j = j0; j < j1; ++j)
      a += sval[j] * bf2f(ego[(size_t)scol[j] * DIN + lane]);
    side[(size_t)row * DIN + lane] = f2bf(a);
  }
}

// -------- bi-interaction via MFMA: out = lrelu((e+s)W1+b1)+lrelu((e*s)W2+b2)
// MTILE=32 rows per tile; 4 waves: WN waves across N, WM waves across M.
template<int DIN, int DOUT, int WM, int WN, int TPB>
__global__ __launch_bounds__(256)
void bi_mfma(const unsigned short* __restrict__ ego,
             const unsigned short* __restrict__ side,
             const float* __restrict__ W1, const float* __restrict__ b1,
             const float* __restrict__ W2, const float* __restrict__ b2,
             unsigned short* __restrict__ out) {
  static_assert(WM * WN == 4, "4 waves");
  constexpr int KFRAG = DIN / 32;
  constexpr int NCOLS = DOUT / WN;
  constexpr int NFRAG = NCOLS / 16;
  constexpr int MROWS = 32 / WM;
  constexpr int MFRAG = MROWS / 16;
  constexpr int CPR   = DIN / 8;           // 16B chunks per row
  constexpr int CHUNKS = 32 * CPR;

  __shared__ __align__(16) unsigned short lds1[32 * DIN];
  __shared__ __align__(16) unsigned short lds2[32 * DIN];

  const int tid  = threadIdx.x;
  const int wid  = tid >> 6;
  const int lane = tid & 63;
  const int n0   = (wid % WN) * NCOLS;
  const int mrow0 = (wid / WN) * MROWS;
  const int lr   = lane & 15;              // fragment row/col index
  const int lk   = (lane >> 4) * 8;        // fragment k offset

  // ---- preload W fragments (f32 global -> bf16 regs) + biases ----
  bf16x8 w1f[KFRAG][NFRAG], w2f[KFRAG][NFRAG];
  #pragma unroll
  for (int kf = 0; kf < KFRAG; ++kf)
    #pragma unroll
    for (int nf = 0; nf < NFRAG; ++nf) {
      int col = n0 + nf * 16 + lr;
      int kr  = kf * 32 + lk;
      bf16x8 a, b;
      #pragma unroll
      for (int j = 0; j < 8; ++j) {
        a[j] = (short)f2bf(W1[(size_t)(kr + j) * DOUT + col]);
        b[j] = (short)f2bf(W2[(size_t)(kr + j) * DOUT + col]);
      }
      w1f[kf][nf] = a; w2f[kf][nf] = b;
    }
  float b1v[NFRAG], b2v[NFRAG];
  #pragma unroll
  for (int nf = 0; nf < NFRAG; ++nf) {
    b1v[nf] = b1[n0 + nf * 16 + lr];
    b2v[nf] = b2[n0 + nf * 16 + lr];
  }

  for (int t = 0; t < TPB; ++t) {
    int row0 = (blockIdx.x * TPB + t) * 32;
    if (row0 >= N_NODES) break;
    __syncthreads();                       // protect LDS from prev-tile readers
    // ---- stage h1 = e+s, h2 = e*s into swizzled LDS (bf16) ----
    for (int ci = tid; ci < CHUNKS; ci += 256) {
      int r  = ci / CPR;
      int c8 = ci % CPR;
      size_t g = (size_t)(row0 + r) * DIN + c8 * 8;
      uint4 e4 = *reinterpret_cast<const uint4*>(ego + g);
      uint4 s4 = *reinterpret_cast<const uint4*>(side + g);
      uint4 h1v, h2v;
      {
        float ex, ey, sx, sy;
        ex = bf2f((unsigned short)(e4.x & 0xFFFFu)); ey = bf2f((unsigned short)(e4.x >> 16));
        sx = bf2f((unsigned short)(s4.x & 0xFFFFu)); sy = bf2f((unsigned short)(s4.x >> 16));
        h1v.x = pack2(ex + sx, ey + sy); h2v.x = pack2(ex * sx, ey * sy);
        ex = bf2f((unsigned short)(e4.y & 0xFFFFu)); ey = bf2f((unsigned short)(e4.y >> 16));
        sx = bf2f((unsigned short)(s4.y & 0xFFFFu)); sy = bf2f((unsigned short)(s4.y >> 16));
        h1v.y = pack2(ex + sx, ey + sy); h2v.y = pack2(ex * sx, ey * sy);
        ex = bf2f((unsigned short)(e4.z & 0xFFFFu)); ey = bf2f((unsigned short)(e4.z >> 16));
        sx = bf2f((unsigned short)(s4.z & 0xFFFFu)); sy = bf2f((unsigned short)(s4.z >> 16));
        h1v.z = pack2(ex + sx, ey + sy); h2v.z = pack2(ex * sx, ey * sy);
        ex = bf2f((unsigned short)(e4.w & 0xFFFFu)); ey = bf2f((unsigned short)(e4.w >> 16));
        sx = bf2f((unsigned short)(s4.w & 0xFFFFu)); sy = bf2f((unsigned short)(s4.w >> 16));
        h1v.w = pack2(ex + sx, ey + sy); h2v.w = pack2(ex * sx, ey * sy);
      }
      unsigned byte = ((unsigned)(r * DIN + c8 * 8)) * 2u;
      byte ^= (unsigned)((r & 7) << 4);    // XOR swizzle, 16B granule
      *reinterpret_cast<uint4*>(reinterpret_cast<char*>(lds1) + byte) = h1v;
      *reinterpret_cast<uint4*>(reinterpret_cast<char*>(lds2) + byte) = h2v;
    }
    __syncthreads();

    // ---- MFMA K-loop ----
    f32x4 acc1[MFRAG][NFRAG], acc2[MFRAG][NFRAG];
    #pragma unroll
    for (int mf = 0; mf < MFRAG; ++mf)
      #pragma unroll
      for (int nf = 0; nf < NFRAG; ++nf) {
        acc1[mf][nf] = (f32x4)0.f;
        acc2[mf][nf] = (f32x4)0.f;
      }
    #pragma unroll
    for (int kf = 0; kf < KFRAG; ++kf) {
      bf16x8 a1[MFRAG], a2[MFRAG];
      #pragma unroll
      for (int mf = 0; mf < MFRAG; ++mf) {
        int r = mrow0 + mf * 16 + lr;
        unsigned byte = ((unsigned)(r * DIN + kf * 32 + lk)) * 2u;
        byte ^= (unsigned)((r & 7) << 4);
        a1[mf] = *reinterpret_cast<const bf16x8*>(reinterpret_cast<const char*>(lds1) + byte);
        a2[mf] = *reinterpret_cast<const bf16x8*>(reinterpret_cast<const char*>(lds2) + byte);
      }
      #pragma unroll
      for (int mf = 0; mf < MFRAG; ++mf)
        #pragma unroll
        for (int nf = 0; nf < NFRAG; ++nf) {
          acc1[mf][nf] = __builtin_amdgcn_mfma_f32_16x16x32_bf16(a1[mf], w1f[kf][nf], acc1[mf][nf], 0, 0, 0);
          acc2[mf][nf] = __builtin_amdgcn_mfma_f32_16x16x32_bf16(a2[mf], w2f[kf][nf], acc2[mf][nf], 0, 0, 0);
        }
    }

    // ---- epilogue: bias + lrelu + sum, store bf16 ----
    #pragma unroll
    for (int mf = 0; mf < MFRAG; ++mf)
      #pragma unroll
      for (int nf = 0; nf < NFRAG; ++nf) {
        #pragma unroll
        for (int reg = 0; reg < 4; ++reg) {
          int r = row0 + mrow0 + mf * 16 + (lane >> 4) * 4 + reg;
          int c = n0 + nf * 16 + lr;
          float o = lrelu(acc1[mf][nf][reg] + b1v[nf]) + lrelu(acc2[mf][nf][reg] + b2v[nf]);
          out[(size_t)r * DOUT + c] = f2bf(o);
        }
      }
  }
}

// -------- per-layer score accumulation (f32 layer-0 variant) ----------------
__global__ __launch_bounds__(256)
void score_f32(const float* __restrict__ emb, int dim,
               const int* __restrict__ uid, const int* __restrict__ pid,
               const int* __restrict__ nid,
               float* __restrict__ pos, float* __restrict__ neg,
               float* __restrict__ l2) {
  int i = blockIdx.x * 4 + (threadIdx.x >> 6);
  int lane = threadIdx.x & 63;
  if (i >= CFB) return;
  const float* u = emb + (size_t)uid[i] * dim;
  const float* p = emb + (size_t)pid[i] * dim;
  const float* g = emb + (size_t)nid[i] * dim;
  float up = 0, un = 0, uu = 0, pp = 0, nn = 0;
  for (int d = lane; d < dim; d += 64) {
    float a = u[d], b = p[d], c = g[d];
    up += a * b;  un += a * c;
    uu += a * a;  pp += b * b;  nn += c * c;
  }
  #pragma unroll
  for (int off = 32; off > 0; off >>= 1) {
    up += __shfl_xor(up, off);
    un += __shfl_xor(un, off);
    uu += __shfl_xor(uu, off);
    pp += __shfl_xor(pp, off);
    nn += __shfl_xor(nn, off);
  }
  if (lane == 0) {
    pos[i] = up; neg[i] = un; l2[i] = uu + pp + nn;
  }
}

// bf16 variant: normalized contribution, accumulates
__global__ __launch_bounds__(256)
void score_bf16(const unsigned short* __restrict__ emb, int dim,
                const int* __restrict__ uid, const int* __restrict__ pid,
                const int* __restrict__ nid,
                float* __restrict__ pos, float* __restrict__ neg,
                float* __restrict__ l2) {
  int i = blockIdx.x * 4 + (threadIdx.x >> 6);
  int lane = threadIdx.x & 63;
  if (i >= CFB) return;
  const unsigned short* u = emb + (size_t)uid[i] * dim;
  const unsigned short* p = emb + (size_t)pid[i] * dim;
  const unsigned short* g = emb + (size_t)nid[i] * dim;
  float up = 0, un = 0, uu = 0, pp = 0, nn = 0;
  for (int d = lane; d < dim; d += 64) {
    float a = bf2f(u[d]), b = bf2f(p[d]), c = bf2f(g[d]);
    up += a * b;  un += a * c;
    uu += a * a;  pp += b * b;  nn += c * c;
  }
  #pragma unroll
  for (int off = 32; off > 0; off >>= 1) {
    up += __shfl_xor(up, off);
    un += __shfl_xor(un, off);
    uu += __shfl_xor(uu, off);
    pp += __shfl_xor(pp, off);
    nn += __shfl_xor(nn, off);
  }
  if (lane == 0) {
    float mu = fmaxf(sqrtf(uu), 1e-12f);
    float mp = fmaxf(sqrtf(pp), 1e-12f);
    float mn = fmaxf(sqrtf(nn), 1e-12f);
    pos[i] += up / (mu * mp);
    neg[i] += un / (mu * mn);
    l2[i]  += uu / (mu * mu) + pp / (mp * mp) + nn / (mn * mn);
  }
}

// ---------------------------- final loss reduce -----------------------------
__global__ __launch_bounds__(256)
void loss_kernel(const float* __restrict__ pos, const float* __restrict__ neg,
                 const float* __restrict__ l2, float* __restrict__ out) {
  __shared__ float s1[256];
  __shared__ float s2[256];
  int tid = threadIdx.x;
  float cf = 0.f, reg = 0.f;
  for (int i = tid; i < CFB; i += 256) {
    float x = pos[i] - neg[i];
    float sp = (x > 0.f) ? log1pf(expf(-x)) : (-x + log1pf(expf(x)));
    cf  += sp;
    reg += l2[i];
  }
  s1[tid] = cf; s2[tid] = reg;
  __syncthreads();
  for (int s = 128; s > 0; s >>= 1) {
    if (tid < s) { s1[tid] += s1[tid + s]; s2[tid] += s2[tid + s]; }
    __syncthreads();
  }
  if (tid == 0)
    out[0] = s1[0] / (float)CFB + 1e-5f * (0.5f * s2[0] / (float)CFB);
}

extern "C" void kernel_launch(void* const* d_in, const int* in_sizes, int n_in,
                              void* d_out, int out_size, void* d_ws, size_t ws_size,
                              hipStream_t stream) {
  const float* embed = (const float*)d_in[0];
  const float* W1_0 = (const float*)d_in[1];
  const float* b1_0 = (const float*)d_in[2];
  const float* W2_0 = (const float*)d_in[3];
  const float* b2_0 = (const float*)d_in[4];
  const float* W1_1 = (const float*)d_in[5];
  const float* b1_1 = (const float*)d_in[6];
  const float* W2_1 = (const float*)d_in[7];
  const float* b2_1 = (const float*)d_in[8];
  const float* W1_2 = (const float*)d_in[9];
  const float* b1_2 = (const float*)d_in[10];
  const float* W2_2 = (const float*)d_in[11];
  const float* b2_2 = (const float*)d_in[12];
  const int*   erows = (const int*)d_in[13];
  const int*   ecols = (const int*)d_in[14];
  const float* evals = (const float*)d_in[15];
  const int*   uid = (const int*)d_in[16];
  const int*   pid = (const int*)d_in[17];
  const int*   nid = (const int*)d_in[18];

  // ---------------- workspace layout (~110 MB) ----------------
  unsigned short* e0 = (unsigned short*)d_ws;               // N*128 bf16 (embed)
  unsigned short* e1 = e0 + (size_t)N_NODES * 128;          // N*128 bf16 (layer0 out)
  unsigned short* e2 = e1 + (size_t)N_NODES * 128;          // N*64
  unsigned short* e3 = e2 + (size_t)N_NODES * 64;           // N*32
  unsigned short* sb = e3 + (size_t)N_NODES * 32;           // N*128 bf16 (side)
  int*   row_ptr = (int*)(sb + (size_t)N_NODES * 128);      // N+1
  int*   cursor  = row_ptr + (N_NODES + 1);                 // N
  int*   bsum    = cursor + N_NODES;                        // 512
  int*   scol    = bsum + 512;                              // NNZ
  float* sval    = (float*)(scol + NNZ);                    // NNZ
  float* posb    = sval + NNZ;
  float* negb    = posb + CFB;
  float* l2b     = negb + CFB;

  // ---------------- CSR build + bf16 convert ----------------
  hipMemsetAsync(cursor, 0, (size_t)N_NODES * sizeof(int), stream);
  cvt_bf16_kernel<<<(N_NODES * 128 / 4 + 255) / 256, 256, 0, stream>>>(embed, e0, N_NODES * 128 / 4);
  hist_kernel<<<(NNZ + 255) / 256, 256, 0, stream>>>(erows, cursor);
  scan_reduce<<<NBLK, 256, 0, stream>>>(cursor, bsum);
  scan_top<<<1, 512, 0, stream>>>(bsum);
  scan_final<<<NBLK, 256, 0, stream>>>(cursor, row_ptr, bsum);
  scatter_kernel<<<(NNZ + 255) / 256, 256, 0, stream>>>(erows, ecols, evals, cursor, scol, sval);

  // layer-0 (raw f32 embedding) contribution; initializes accumulators
  score_f32<<<CFB / 4, 256, 0, stream>>>(embed, 128, uid, pid, nid, posb, negb, l2b);

  constexpr int TPB = 5;                      // 3125 tiles / 625 blocks
  constexpr int GB  = (N_NODES / 32 + TPB - 1) / TPB;

  // ---- layer 0: 128 -> 128 ----
  spmm_bf16<128><<<(N_NODES + 3) / 4, 256, 0, stream>>>(e0, row_ptr, scol, sval, sb);
  bi_mfma<128, 128, 1, 4, TPB><<<GB, 256, 0, stream>>>(e0, sb, W1_0, b1_0, W2_0, b2_0, e1);
  score_bf16<<<CFB / 4, 256, 0, stream>>>(e1, 128, uid, pid, nid, posb, negb, l2b);

  // ---- layer 1: 128 -> 64 ----
  spmm_bf16<128><<<(N_NODES + 3) / 4, 256, 0, stream>>>(e1, row_ptr, scol, sval, sb);
  bi_mfma<128, 64, 1, 4, TPB><<<GB, 256, 0, stream>>>(e1, sb, W1_1, b1_1, W2_1, b2_1, e2);
  score_bf16<<<CFB / 4, 256, 0, stream>>>(e2, 64, uid, pid, nid, posb, negb, l2b);

  // ---- layer 2: 64 -> 32 ----
  spmm_bf16<64><<<(N_NODES + 3) / 4, 256, 0, stream>>>(e2, row_ptr, scol, sval, sb);
  bi_mfma<64, 32, 2, 2, TPB><<<GB, 256, 0, stream>>>(e2, sb, W1_2, b1_2, W2_2, b2_2, e3);
  score_bf16<<<CFB / 4, 256, 0, stream>>>(e3, 32, uid, pid, nid, posb, negb, l2b);

  loss_kernel<<<1, 256, 0, stream>>>(posb, negb, l2b, (float*)d_out);
}

// Round 4
// 519.941 us; speedup vs baseline: 13.5810x; 1.0034x over previous
//
#include <hip/hip_runtime.h>
#include <math.h>

static constexpr int N_NODES = 100000;
static constexpr int NNZ     = 1600000;
static constexpr int CFB     = 8192;
static constexpr int NBLK    = (N_NODES + 255) / 256;   // 391 scan blocks

typedef short bf16x8 __attribute__((ext_vector_type(8)));
typedef float f32x4  __attribute__((ext_vector_type(4)));

__device__ __forceinline__ float lrelu(float x) { return x >= 0.0f ? x : 0.01f * x; }

__device__ __forceinline__ unsigned short f2bf(float x) {
  unsigned u = __float_as_uint(x);
  u += 0x7FFFu + ((u >> 16) & 1u);          // round-to-nearest-even
  return (unsigned short)(u >> 16);
}
__device__ __forceinline__ float bf2f(unsigned short h) {
  return __uint_as_float(((unsigned)h) << 16);
}
__device__ __forceinline__ unsigned pack2(float x, float y) {
  return (unsigned)f2bf(x) | ((unsigned)f2bf(y) << 16);
}

// ---------- fused: f32->bf16 convert (first n4 threads) + row histogram -----
__global__ __launch_bounds__(256)
void cvt_hist_kernel(const float* __restrict__ in, unsigned short* __restrict__ out, int n4,
                     const int* __restrict__ erows, int* __restrict__ cnt) {
  int i = blockIdx.x * 256 + threadIdx.x;
  if (i < n4) {
    float4 v = reinterpret_cast<const float4*>(in)[i];
    uint2 o; o.x = pack2(v.x, v.y); o.y = pack2(v.z, v.w);
    reinterpret_cast<uint2*>(out)[i] = o;
  }
  if (i < NNZ) atomicAdd(&cnt[erows[i]], 1);
}

// ---------------------- CSR build: scans --------------------------------
__global__ __launch_bounds__(256)
void scan_reduce(const int* __restrict__ cnt, int* __restrict__ bsum) {
  __shared__ int s[256];
  int i = blockIdx.x * 256 + threadIdx.x;
  s[threadIdx.x] = (i < N_NODES) ? cnt[i] : 0;
  __syncthreads();
  for (int st = 128; st > 0; st >>= 1) {
    if (threadIdx.x < st) s[threadIdx.x] += s[threadIdx.x + st];
    __syncthreads();
  }
  if (threadIdx.x == 0) bsum[blockIdx.x] = s[0];
}

__global__ __launch_bounds__(512)
void scan_top(int* __restrict__ bsum) {
  __shared__ int s[512];
  int t = threadIdx.x;
  int v0 = (t < NBLK) ? bsum[t] : 0;
  s[t] = v0;
  __syncthreads();
  for (int off = 1; off < 512; off <<= 1) {
    int v = (t >= off) ? s[t - off] : 0;
    __syncthreads();
    s[t] += v;
    __syncthreads();
  }
  if (t < NBLK) bsum[t] = s[t] - v0;
}

__global__ __launch_bounds__(256)
void scan_final(int* __restrict__ cnt_off, int* __restrict__ row_ptr,
                const int* __restrict__ bsum) {
  __shared__ int s[256];
  int t = threadIdx.x;
  int i = blockIdx.x * 256 + t;
  int v = (i < N_NODES) ? cnt_off[i] : 0;
  s[t] = v;
  __syncthreads();
  for (int off = 1; off < 256; off <<= 1) {
    int x = (t >= off) ? s[t - off] : 0;
    __syncthreads();
    s[t] += x;
    __syncthreads();
  }
  int excl = s[t] - v + bsum[blockIdx.x];
  if (i < N_NODES) { row_ptr[i] = excl; cnt_off[i] = excl; }
  if (i == 0) row_ptr[N_NODES] = NNZ;
}

// ----------- scatter: single packed 8B record (col, valbits) per edge -------
__global__ __launch_bounds__(256)
void scatter_kernel(const int* __restrict__ erows, const int* __restrict__ ecols,
                    const float* __restrict__ evals, int* __restrict__ cursor,
                    uint2* __restrict__ spack) {
  int i = blockIdx.x * 256 + threadIdx.x;
  if (i < NNZ) {
    int r = erows[i];
    int p = atomicAdd(&cursor[r], 1);
    uint2 rec;
    rec.x = (unsigned)ecols[i];
    rec.y = __float_as_uint(evals[i]);
    spack[p] = rec;
  }
}

// ---------------- SpMM (CSR, bf16): one wave per row ------------------------
template<int DIN>
__global__ __launch_bounds__(256)
void spmm_bf16(const unsigned short* __restrict__ ego,
               const int* __restrict__ row_ptr,
               const uint2* __restrict__ spack,
               unsigned short* __restrict__ side) {
  int row  = blockIdx.x * 4 + (threadIdx.x >> 6);
  int lane = threadIdx.x & 63;
  if (row >= N_NODES) return;
  int j0 = row_ptr[row], j1 = row_ptr[row + 1];
  if constexpr (DIN == 128) {
    float ax = 0.f, ay = 0.f;
    #pragma unroll 8
    for (int j = j0; j < j1; ++j) {
      uint2 rec = spack[j];
      float v = __uint_as_float(rec.y);
      unsigned x = *reinterpret_cast<const unsigned*>(ego + (size_t)rec.x * 128 + lane * 2);
      ax += v * bf2f((unsigned short)(x & 0xFFFFu));
      ay += v * bf2f((unsigned short)(x >> 16));
    }
    *reinterpret_cast<unsigned*>(side + (size_t)row * 128 + lane * 2) = pack2(ax, ay);
  } else {
    float a = 0.f;
    #pragma unroll 8
    for (int j = j0; j < j1; ++j) {
      uint2 rec = spack[j];
      a += __uint_as_float(rec.y) * bf2f(ego[(size_t)rec.x * DIN + lane]);
    }
    side[(size_t)row * DIN + lane] = f2bf(a);
  }
}

// -------- bi-interaction via MFMA: out = lrelu((e+s)W1+b1)+lrelu((e*s)W2+b2)
template<int DIN, int DOUT, int WM, int WN, int TPB>
__global__ __launch_bounds__(256)
void bi_mfma(const unsigned short* __restrict__ ego,
             const unsigned short* __restrict__ side,
             const float* __restrict__ W1, const float* __restrict__ b1,
             const float* __restrict__ W2, const float* __restrict__ b2,
             unsigned short* __restrict__ out) {
  static_assert(WM * WN == 4, "4 waves");
  constexpr int KFRAG = DIN / 32;
  constexpr int NCOLS = DOUT / WN;
  constexpr int NFRAG = NCOLS / 16;
  constexpr int MROWS = 32 / WM;
  constexpr int MFRAG = MROWS / 16;
  constexpr int CPR   = DIN / 8;
  constexpr int CHUNKS = 32 * CPR;

  __shared__ __align__(16) unsigned short lds1[32 * DIN];
  __shared__ __align__(16) unsigned short lds2[32 * DIN];

  const int tid  = threadIdx.x;
  const int wid  = tid >> 6;
  const int lane = tid & 63;
  const int n0   = (wid % WN) * NCOLS;
  const int mrow0 = (wid / WN) * MROWS;
  const int lr   = lane & 15;
  const int lk   = (lane >> 4) * 8;

  bf16x8 w1f[KFRAG][NFRAG], w2f[KFRAG][NFRAG];
  #pragma unroll
  for (int kf = 0; kf < KFRAG; ++kf)
    #pragma unroll
    for (int nf = 0; nf < NFRAG; ++nf) {
      int col = n0 + nf * 16 + lr;
      int kr  = kf * 32 + lk;
      bf16x8 a, b;
      #pragma unroll
      for (int j = 0; j < 8; ++j) {
        a[j] = (short)f2bf(W1[(size_t)(kr + j) * DOUT + col]);
        b[j] = (short)f2bf(W2[(size_t)(kr + j) * DOUT + col]);
      }
      w1f[kf][nf] = a; w2f[kf][nf] = b;
    }
  float b1v[NFRAG], b2v[NFRAG];
  #pragma unroll
  for (int nf = 0; nf < NFRAG; ++nf) {
    b1v[nf] = b1[n0 + nf * 16 + lr];
    b2v[nf] = b2[n0 + nf * 16 + lr];
  }

  for (int t = 0; t < TPB; ++t) {
    int row0 = (blockIdx.x * TPB + t) * 32;
    if (row0 >= N_NODES) break;
    __syncthreads();
    for (int ci = tid; ci < CHUNKS; ci += 256) {
      int r  = ci / CPR;
      int c8 = ci % CPR;
      size_t g = (size_t)(row0 + r) * DIN + c8 * 8;
      uint4 e4 = *reinterpret_cast<const uint4*>(ego + g);
      uint4 s4 = *reinterpret_cast<const uint4*>(side + g);
      uint4 h1v, h2v;
      {
        float ex, ey, sx, sy;
        ex = bf2f((unsigned short)(e4.x & 0xFFFFu)); ey = bf2f((unsigned short)(e4.x >> 16));
        sx = bf2f((unsigned short)(s4.x & 0xFFFFu)); sy = bf2f((unsigned short)(s4.x >> 16));
        h1v.x = pack2(ex + sx, ey + sy); h2v.x = pack2(ex * sx, ey * sy);
        ex = bf2f((unsigned short)(e4.y & 0xFFFFu)); ey = bf2f((unsigned short)(e4.y >> 16));
        sx = bf2f((unsigned short)(s4.y & 0xFFFFu)); sy = bf2f((unsigned short)(s4.y >> 16));
        h1v.y = pack2(ex + sx, ey + sy); h2v.y = pack2(ex * sx, ey * sy);
        ex = bf2f((unsigned short)(e4.z & 0xFFFFu)); ey = bf2f((unsigned short)(e4.z >> 16));
        sx = bf2f((unsigned short)(s4.z & 0xFFFFu)); sy = bf2f((unsigned short)(s4.z >> 16));
        h1v.z = pack2(ex + sx, ey + sy); h2v.z = pack2(ex * sx, ey * sy);
        ex = bf2f((unsigned short)(e4.w & 0xFFFFu)); ey = bf2f((unsigned short)(e4.w >> 16));
        sx = bf2f((unsigned short)(s4.w & 0xFFFFu)); sy = bf2f((unsigned short)(s4.w >> 16));
        h1v.w = pack2(ex + sx, ey + sy); h2v.w = pack2(ex * sx, ey * sy);
      }
      unsigned byte = ((unsigned)(r * DIN + c8 * 8)) * 2u;
      byte ^= (unsigned)((r & 7) << 4);
      *reinterpret_cast<uint4*>(reinterpret_cast<char*>(lds1) + byte) = h1v;
      *reinterpret_cast<uint4*>(reinterpret_cast<char*>(lds2) + byte) = h2v;
    }
    __syncthreads();

    f32x4 acc1[MFRAG][NFRAG], acc2[MFRAG][NFRAG];
    #pragma unroll
    for (int mf = 0; mf < MFRAG; ++mf)
      #pragma unroll
      for (int nf = 0; nf < NFRAG; ++nf) {
        acc1[mf][nf] = (f32x4)0.f;
        acc2[mf][nf] = (f32x4)0.f;
      }
    #pragma unroll
    for (int kf = 0; kf < KFRAG; ++kf) {
      bf16x8 a1[MFRAG], a2[MFRAG];
      #pragma unroll
      for (int mf = 0; mf < MFRAG; ++mf) {
        int r = mrow0 + mf * 16 + lr;
        unsigned byte = ((unsigned)(r * DIN + kf * 32 + lk)) * 2u;
        byte ^= (unsigned)((r & 7) << 4);
        a1[mf] = *reinterpret_cast<const bf16x8*>(reinterpret_cast<const char*>(lds1) + byte);
        a2[mf] = *reinterpret_cast<const bf16x8*>(reinterpret_cast<const char*>(lds2) + byte);
      }
      #pragma unroll
      for (int mf = 0; mf < MFRAG; ++mf)
        #pragma unroll
        for (int nf = 0; nf < NFRAG; ++nf) {
          acc1[mf][nf] = __builtin_amdgcn_mfma_f32_16x16x32_bf16(a1[mf], w1f[kf][nf], acc1[mf][nf], 0, 0, 0);
          acc2[mf][nf] = __builtin_amdgcn_mfma_f32_16x16x32_bf16(a2[mf], w2f[kf][nf], acc2[mf][nf], 0, 0, 0);
        }
    }

    #pragma unroll
    for (int mf = 0; mf < MFRAG; ++mf)
      #pragma unroll
      for (int nf = 0; nf < NFRAG; ++nf) {
        #pragma unroll
        for (int reg = 0; reg < 4; ++reg) {
          int r = row0 + mrow0 + mf * 16 + (lane >> 4) * 4 + reg;
          int c = n0 + nf * 16 + lr;
          float o = lrelu(acc1[mf][nf][reg] + b1v[nf]) + lrelu(acc2[mf][nf][reg] + b2v[nf]);
          out[(size_t)r * DOUT + c] = f2bf(o);
        }
      }
  }
}

// -------- per-layer score accumulation ----------------
__global__ __launch_bounds__(256)
void score_f32(const float* __restrict__ emb, int dim,
               const int* __restrict__ uid, const int* __restrict__ pid,
               const int* __restrict__ nid,
               float* __restrict__ pos, float* __restrict__ neg,
               float* __restrict__ l2) {
  int i = blockIdx.x * 4 + (threadIdx.x >> 6);
  int lane = threadIdx.x & 63;
  if (i >= CFB) return;
  const float* u = emb + (size_t)uid[i] * dim;
  const float* p = emb + (size_t)pid[i] * dim;
  const float* g = emb + (size_t)nid[i] * dim;
  float up = 0, un = 0, uu = 0, pp = 0, nn = 0;
  for (int d = lane; d < dim; d += 64) {
    float a = u[d], b = p[d], c = g[d];
    up += a * b;  un += a * c;
    uu += a * a;  pp += b * b;  nn += c * c;
  }
  #pragma unroll
  for (int off = 32; off > 0; off >>= 1) {
    up += __shfl_xor(up, off);
    un += __shfl_xor(un, off);
    uu += __shfl_xor(uu, off);
    pp += __shfl_xor(pp, off);
    nn += __shfl_xor(nn, off);
  }
  if (lane == 0) {
    pos[i] = up; neg[i] = un; l2[i] = uu + pp + nn;
  }
}

__global__ __launch_bounds__(256)
void score_bf16(const unsigned short* __restrict__ emb, int dim,
                const int* __restrict__ uid, const int* __restrict__ pid,
                const int* __restrict__ nid,
                float* __restrict__ pos, float* __restrict__ neg,
                float* __restrict__ l2) {
  int i = blockIdx.x * 4 + (threadIdx.x >> 6);
  int lane = threadIdx.x & 63;
  if (i >= CFB) return;
  const unsigned short* u = emb + (size_t)uid[i] * dim;
  const unsigned short* p = emb + (size_t)pid[i] * dim;
  const unsigned short* g = emb + (size_t)nid[i] * dim;
  float up = 0, un = 0, uu = 0, pp = 0, nn = 0;
  for (int d = lane; d < dim; d += 64) {
    float a = bf2f(u[d]), b = bf2f(p[d]), c = bf2f(g[d]);
    up += a * b;  un += a * c;
    uu += a * a;  pp += b * b;  nn += c * c;
  }
  #pragma unroll
  for (int off = 32; off > 0; off >>= 1) {
    up += __shfl_xor(up, off);
    un += __shfl_xor(un, off);
    uu += __shfl_xor(uu, off);
    pp += __shfl_xor(pp, off);
    nn += __shfl_xor(nn, off);
  }
  if (lane == 0) {
    float mu = fmaxf(sqrtf(uu), 1e-12f);
    float mp = fmaxf(sqrtf(pp), 1e-12f);
    float mn = fmaxf(sqrtf(nn), 1e-12f);
    pos[i] += up / (mu * mp);
    neg[i] += un / (mu * mn);
    l2[i]  += uu / (mu * mu) + pp / (mp * mp) + nn / (mn * mn);
  }
}

// ---------------------------- final loss reduce -----------------------------
__global__ __launch_bounds__(256)
void loss_kernel(const float* __restrict__ pos, const float* __restrict__ neg,
                 const float* __restrict__ l2, float* __restrict__ out) {
  __shared__ float s1[256];
  __shared__ float s2[256];
  int tid = threadIdx.x;
  float cf = 0.f, reg = 0.f;
  for (int i = tid; i < CFB; i += 256) {
    float x = pos[i] - neg[i];
    float sp = (x > 0.f) ? log1pf(expf(-x)) : (-x + log1pf(expf(x)));
    cf  += sp;
    reg += l2[i];
  }
  s1[tid] = cf; s2[tid] = reg;
  __syncthreads();
  for (int s = 128; s > 0; s >>= 1) {
    if (tid < s) { s1[tid] += s1[tid + s]; s2[tid] += s2[tid + s]; }
    __syncthreads();
  }
  if (tid == 0)
    out[0] = s1[0] / (float)CFB + 1e-5f * (0.5f * s2[0] / (float)CFB);
}

extern "C" void kernel_launch(void* const* d_in, const int* in_sizes, int n_in,
                              void* d_out, int out_size, void* d_ws, size_t ws_size,
                              hipStream_t stream) {
  const float* embed = (const float*)d_in[0];
  const float* W1_0 = (const float*)d_in[1];
  const float* b1_0 = (const float*)d_in[2];
  const float* W2_0 = (const float*)d_in[3];
  const float* b2_0 = (const float*)d_in[4];
  const float* W1_1 = (const float*)d_in[5];
  const float* b1_1 = (const float*)d_in[6];
  const float* W2_1 = (const float*)d_in[7];
  const float* b2_1 = (const float*)d_in[8];
  const float* W1_2 = (const float*)d_in[9];
  const float* b1_2 = (const float*)d_in[10];
  const float* W2_2 = (const float*)d_in[11];
  const float* b2_2 = (const float*)d_in[12];
  const int*   erows = (const int*)d_in[13];
  const int*   ecols = (const int*)d_in[14];
  const float* evals = (const float*)d_in[15];
  const int*   uid = (const int*)d_in[16];
  const int*   pid = (const int*)d_in[17];
  const int*   nid = (const int*)d_in[18];

  // ---------------- workspace layout ----------------
  unsigned short* e0 = (unsigned short*)d_ws;               // N*128 bf16
  unsigned short* e1 = e0 + (size_t)N_NODES * 128;          // N*128
  unsigned short* e2 = e1 + (size_t)N_NODES * 128;          // N*64
  unsigned short* e3 = e2 + (size_t)N_NODES * 64;           // N*32
  unsigned short* sb = e3 + (size_t)N_NODES * 32;           // N*128 (side)
  int*   row_ptr = (int*)(sb + (size_t)N_NODES * 128);      // N+1
  int*   cursor  = row_ptr + (N_NODES + 1);                 // N
  int*   bsum    = cursor + N_NODES;                        // 512
  uint2* spack   = (uint2*)(bsum + 512);                    // NNZ packed (col,val)
  float* posb    = (float*)(spack + NNZ);
  float* negb    = posb + CFB;
  float* l2b     = negb + CFB;

  // ---------------- CSR build + bf16 convert ----------------
  hipMemsetAsync(cursor, 0, (size_t)N_NODES * sizeof(int), stream);
  cvt_hist_kernel<<<(NNZ + 255) / 256, 256, 0, stream>>>(embed, e0, N_NODES * 128 / 4, erows, cursor);
  scan_reduce<<<NBLK, 256, 0, stream>>>(cursor, bsum);
  scan_top<<<1, 512, 0, stream>>>(bsum);
  scan_final<<<NBLK, 256, 0, stream>>>(cursor, row_ptr, bsum);
  scatter_kernel<<<(NNZ + 255) / 256, 256, 0, stream>>>(erows, ecols, evals, cursor, spack);

  // layer-0 (raw f32 embedding) contribution; initializes accumulators
  score_f32<<<CFB / 4, 256, 0, stream>>>(embed, 128, uid, pid, nid, posb, negb, l2b);

  constexpr int TPB = 5;
  constexpr int GB  = (N_NODES / 32 + TPB - 1) / TPB;

  // ---- layer 0: 128 -> 128 ----
  spmm_bf16<128><<<(N_NODES + 3) / 4, 256, 0, stream>>>(e0, row_ptr, spack, sb);
  bi_mfma<128, 128, 1, 4, TPB><<<GB, 256, 0, stream>>>(e0, sb, W1_0, b1_0, W2_0, b2_0, e1);
  score_bf16<<<CFB / 4, 256, 0, stream>>>(e1, 128, uid, pid, nid, posb, negb, l2b);

  // ---- layer 1: 128 -> 64 ----
  spmm_bf16<128><<<(N_NODES + 3) / 4, 256, 0, stream>>>(e1, row_ptr, spack, sb);
  bi_mfma<128, 64, 1, 4, TPB><<<GB, 256, 0, stream>>>(e1, sb, W1_1, b1_1, W2_1, b2_1, e2);
  score_bf16<<<CFB / 4, 256, 0, stream>>>(e2, 64, uid, pid, nid, posb, negb, l2b);

  // ---- layer 2: 64 -> 32 ----
  spmm_bf16<64><<<(N_NODES + 3) / 4, 256, 0, stream>>>(e2, row_ptr, spack, sb);
  bi_mfma<64, 32, 2, 2, TPB><<<GB, 256, 0, stream>>>(e2, sb, W1_2, b1_2, W2_2, b2_2, e3);
  score_bf16<<<CFB / 4, 256, 0, stream>>>(e3, 32, uid, pid, nid, posb, negb, l2b);

  loss_kernel<<<1, 256, 0, stream>>>(posb, negb, l2b, (float*)d_out);
}